// Round 5
// baseline (187.358 us; speedup 1.0000x reference)
//
#include <hip/hip_runtime.h>
#include <math.h>

#define KCH 32          // channels k
#define Q 64            // taps q

// ---- fused geometry ----
#define LCH 28          // chunk length (new steps per chunk)
#define WSC 12          // warm-up steps (contraction ~0.011/step -> 1e-23)
#define CHB 8           // chunks per block
#define NSTEP (CHB * LCH)     // 224 new steps per block
#define NTILES 15             // MFMA 16-step tiles (covers 240 >= 236 comp steps)
#define ROWS (NTILES * 16)    // 240 Sl rows
#define SROW 36               // Sl row stride (16B-aligned, benign conflicts)
#define STG 312               // staged window entries
#define USTR2 320             // staging array stride (ushorts)

typedef __attribute__((ext_vector_type(8))) short short8;
typedef __attribute__((ext_vector_type(4))) float float4v;

__device__ __forceinline__ float sp_softplus(float x) {
    return (x > 15.f) ? x : log1pf(expf(x));
}

__device__ __forceinline__ unsigned short f2bf(float f) {
    union { float f; unsigned int u; } v; v.f = f;
    unsigned int u = v.u;
    unsigned int r = (u + 0x7FFFu + ((u >> 16) & 1u)) >> 16;   // RNE
    return (unsigned short)r;
}

// butterfly sum over lanes within each quad (lanes 0..3), via DPP quad_perm
__device__ __forceinline__ float quad_sum4(float v) {
    int vi = __float_as_int(v);
    int p1 = __builtin_amdgcn_update_dpp(0, vi, 0xB1, 0xF, 0xF, true); // xor 1
    v += __int_as_float(p1);
    vi = __float_as_int(v);
    int p2 = __builtin_amdgcn_update_dpp(0, vi, 0x4E, 0xF, 0xF, true); // xor 2
    v += __int_as_float(p2);
    return v;
}

// ws layout (floats):
// [0]=sum_u2 [1]=sum_u2sq [2]=var [3]=sigma2_init [4]=acc_sumlog
// [5]=acc_sumratio [6]=beta0 [7]=counter_k1(int) [8..40)=beta [40..72)=rho
// [72..104)=w0 [104]=counter_scan(int)
// [4352..6400) : bf16 Wc[128][32] as ushort (4096 ush)
#define WOFF_BF16W 4352

// --- K12: stats + (last block) param preprocessing -----------------------
extern "C" __global__ void k12_stats(const float* __restrict__ r,
                                     const float* __restrict__ a0p,
                                     const float* __restrict__ a1p,
                                     const float* __restrict__ rb0,
                                     const float* __restrict__ rb,
                                     const float* __restrict__ rw0,
                                     const float* __restrict__ rw,
                                     const float* __restrict__ rg,
                                     const float* __restrict__ rr,
                                     float* __restrict__ wsf,
                                     int n, int nblocks) {
    const float a0 = a0p[0], a1 = a1p[0];
    float s1 = 0.f, s2 = 0.f;
    for (int t = blockIdx.x * blockDim.x + threadIdx.x; t < n;
         t += gridDim.x * blockDim.x) {
        float u = r[t + 1] - a0 - a1 * r[t];
        float u2 = u * u;
        s1 += u2;
        s2 += u2 * u2;
    }
#pragma unroll
    for (int off = 32; off > 0; off >>= 1) {
        s1 += __shfl_down(s1, off);
        s2 += __shfl_down(s2, off);
    }
    __shared__ float b1[4], b2[4];
    __shared__ int lastflag;
    int wid = threadIdx.x >> 6;
    if ((threadIdx.x & 63) == 0) { b1[wid] = s1; b2[wid] = s2; }
    __syncthreads();
    if (threadIdx.x == 0) {
        float t1 = b1[0] + b1[1] + b1[2] + b1[3];
        float t2 = b2[0] + b2[1] + b2[2] + b2[3];
        atomicAdd(&wsf[0], t1);
        atomicAdd(&wsf[1], t2);
        __threadfence();
        int old = atomicAdd((int*)(wsf + 7), 1);
        lastflag = (old == nblocks - 1) ? 1 : 0;
    }
    __syncthreads();
    if (!lastflag) return;

    const int tid = threadIdx.x;
    if (tid == 0) {
        float t1 = atomicAdd(&wsf[0], 0.f);
        float t2 = atomicAdd(&wsf[1], 0.f);
        float nf = (float)n;
        float mean = t1 / nf;
        float var = fmaxf((t2 - nf * mean * mean) / (nf - 1.f), 0.f);
        wsf[2] = var;
        wsf[3] = var + 1e-6f;
        wsf[6] = sp_softplus(rb0[0]);
    }
    if (tid < KCH) {
        wsf[8 + tid]  = sp_softplus(rb[tid]);
        wsf[40 + tid] = sp_softplus(rr[tid]);
        wsf[72 + tid] = sp_softplus(rw0[tid]);
    }
    unsigned short* Wb = (unsigned short*)(wsf + WOFF_BF16W);
    for (int idx = tid; idx < 2 * KCH * Q; idx += blockDim.x) {
        int k = idx >> 5;        // 0..127 (taps already reversed)
        int i = idx & 31;        // channel
        float raw = (k < Q) ? rw[i * Q + (Q - 1 - k)]
                            : rg[i * Q + (Q - 1 - (k - Q))];
        Wb[idx] = f2bf(sp_softplus(raw));
    }
}

// --- KF: fused MFMA conv (-> LDS) + chunked scan + NLL -------------------
extern "C" __global__ void __launch_bounds__(256, 4)
k_fused(const float* __restrict__ r, const float* __restrict__ vol,
        const float* __restrict__ a0p, const float* __restrict__ a1p,
        float* __restrict__ wsf, float* __restrict__ out,
        int n, int nblocks) {
    __shared__ __attribute__((aligned(16))) float Sl[ROWS][SROW];
    __shared__ __attribute__((aligned(16))) unsigned short UVs[4 * USTR2];
    __shared__ float Uf[ROWS];

    unsigned short* Ue = UVs;
    unsigned short* Uo = UVs + USTR2;
    unsigned short* Ve = UVs + 2 * USTR2;
    unsigned short* Vo = UVs + 3 * USTR2;

    const int b = blockIdx.x;
    const int tid = threadIdx.x;
    const int tb = (b == 0) ? 0 : (NSTEP * b - WSC);   // t of Sl row 0
    const float a0 = a0p[0], a1 = a1p[0];
    const float var = wsf[2];
    const float vol0 = vol[0];

    // ---- stage bf16 u2/vol windows (even + odd copies) + fp32 u2 --------
    for (int xs = tid; xs < STG; xs += 256) {
        int f = tb + xs;                // index into u2_full/vol_full space
        float uval, vval;
        if (f < Q) {
            uval = var;
            vval = vol0;
        } else {
            int t = f - Q;
            uval = 0.f; vval = 0.f;
            if (t < n) {
                float u = r[t + 1] - a0 - a1 * r[t];
                uval = u * u;
                vval = vol[t];
            }
        }
        unsigned short ub = f2bf(uval), vb = f2bf(vval);
        Ue[xs] = ub; Ve[xs] = vb;
        if (xs > 0) { Uo[xs - 1] = ub; Vo[xs - 1] = vb; }
        int i = xs - Q;
        if (i >= 0 && i < ROWS) Uf[i] = uval;   // fp32 u2 for ratio term
    }

    const int lane = tid & 63;
    const int ln = lane & 15;
    const int q4 = (lane >> 4) & 3;
    const int q8 = q4 * 8;
    const int wv = tid >> 6;

    // B-fragments: Wc[128][32]; lane holds B[c*32 + q8 + j][h*16 + ln]
    const unsigned short* Wb = (const unsigned short*)(wsf + WOFF_BF16W);
    short8 bf[4][2];
#pragma unroll
    for (int c = 0; c < 4; c++)
#pragma unroll
        for (int h = 0; h < 2; h++)
#pragma unroll
            for (int j = 0; j < 8; j++)
                bf[c][h][j] = (short)Wb[(c * 32 + q8 + j) * 32 + h * 16 + ln];
    const float w00 = wsf[72 + ln];
    const float w01 = wsf[72 + 16 + ln];

    __syncthreads();

    // ---- MFMA conv: 15 tiles of 16 steps, round-robin across 4 waves ----
    const unsigned int* pUe = (const unsigned int*)Ue;
    const unsigned int* pUo = (const unsigned int*)Uo;
    const unsigned int* pVe = (const unsigned int*)Ve;
    const unsigned int* pVo = (const unsigned int*)Vo;

    for (int tile = wv; tile < NTILES; tile += 4) {
        const int st = tile * 16;
        float4v acc0 = {0.f, 0.f, 0.f, 0.f};
        float4v acc1 = {0.f, 0.f, 0.f, 0.f};
#pragma unroll
        for (int c = 0; c < 4; c++) {
            int e0 = st + ln + (c & 1) * 32 + q8;   // first of 8 A elements
            const unsigned int* pe = (c < 2) ? pUe : pVe;
            const unsigned int* po = (c < 2) ? pUo : pVo;
            const unsigned int* p = (e0 & 1) ? po : pe;
            int hx = e0 >> 1;
            union { unsigned int w[4]; short8 s; } A;
            A.w[0] = p[hx];
            A.w[1] = p[hx + 1];
            A.w[2] = p[hx + 2];
            A.w[3] = p[hx + 3];
            acc0 = __builtin_amdgcn_mfma_f32_16x16x32_bf16(A.s, bf[c][0], acc0, 0, 0, 0);
            acc1 = __builtin_amdgcn_mfma_f32_16x16x32_bf16(A.s, bf[c][1], acc1, 0, 0, 0);
        }
        const int rowb = st + q4 * 4;               // C/D: row=(lane>>4)*4+reg
#pragma unroll
        for (int rg_ = 0; rg_ < 4; rg_++) {
            Sl[rowb + rg_][ln]      = acc0[rg_] + w00;
            Sl[rowb + rg_][16 + ln] = acc1[rg_] + w01;
        }
    }
    __syncthreads();

    // ---- scan: wave 0 only, quad per chunk, LDS-fed with row prefetch ---
    if (wv != 0) return;

    const int quad = lane >> 2;
    const int laneq = lane & 3;
    float rho_c[8], beta_c[8];
#pragma unroll
    for (int e = 0; e < 8; e++) {
        rho_c[e]  = wsf[40 + laneq * 8 + e];
        beta_c[e] = wsf[8 + laneq * 8 + e];
    }
    const float bconst = wsf[6] + 1e-8f;    // beta0 + 1e-8
    float sig = wsf[3];                     // sigma2_init warm start
    float sumlog = 0.f, sumratio = 0.f;

    int i0 = 0, warm = 0, send = 0;
    if (quad < CHB) {
        int cstart = NSTEP * b + LCH * quad;
        if (b == 0) {
            warm = (quad == 0) ? 0 : WSC;
            i0 = LCH * quad - warm;
        } else {
            warm = WSC;
            i0 = LCH * quad;
        }
        if (cstart < n) send = warm + min(LCH, n - cstart);
    }

    float4 A = *reinterpret_cast<const float4*>(&Sl[i0][laneq * 8]);
    float4 B = *reinterpret_cast<const float4*>(&Sl[i0][laneq * 8 + 4]);
    for (int s2 = 0; s2 < send; s2++) {
        const int i = i0 + s2;
        float4 An = *reinterpret_cast<const float4*>(&Sl[i + 1][laneq * 8]);
        float4 Bn = *reinterpret_cast<const float4*>(&Sl[i + 1][laneq * 8 + 4]);
        float uu = Uf[i];
        float h0 = fmaxf(fmaf(rho_c[0], sig, A.x), 0.f);
        float h1 = fmaxf(fmaf(rho_c[1], sig, A.y), 0.f);
        float h2 = fmaxf(fmaf(rho_c[2], sig, A.z), 0.f);
        float h3 = fmaxf(fmaf(rho_c[3], sig, A.w), 0.f);
        float h4 = fmaxf(fmaf(rho_c[4], sig, B.x), 0.f);
        float h5 = fmaxf(fmaf(rho_c[5], sig, B.y), 0.f);
        float h6 = fmaxf(fmaf(rho_c[6], sig, B.z), 0.f);
        float h7 = fmaxf(fmaf(rho_c[7], sig, B.w), 0.f);
        float p0 = beta_c[0] * h0;
        float p1 = beta_c[1] * h1;
        p0 = fmaf(beta_c[2], h2, p0);
        p1 = fmaf(beta_c[3], h3, p1);
        p0 = fmaf(beta_c[4], h4, p0);
        p1 = fmaf(beta_c[5], h5, p1);
        p0 = fmaf(beta_c[6], h6, p0);
        p1 = fmaf(beta_c[7], h7, p1);
        float dsum = quad_sum4(p0 + p1);
        sig = bconst + dsum;
        bool live = (s2 >= warm);
        sumlog   += live ? __logf(sig) : 0.f;
        sumratio += live ? uu * __builtin_amdgcn_rcpf(sig) : 0.f;
        A = An; B = Bn;
    }

    if (laneq != 0) { sumlog = 0.f; sumratio = 0.f; }
#pragma unroll
    for (int off = 32; off > 0; off >>= 1) {
        sumlog   += __shfl_down(sumlog, off);
        sumratio += __shfl_down(sumratio, off);
    }
    if (lane == 0) {
        atomicAdd(&wsf[4], sumlog);
        atomicAdd(&wsf[5], sumratio);
        __threadfence();
        int old = atomicAdd((int*)(wsf + 104), 1);
        if (old == nblocks - 1) {
            float sl = atomicAdd(&wsf[4], 0.f);
            float sr = atomicAdd(&wsf[5], 0.f);
            double cst = 0.5 * (double)n * 1.8378770664093454;  // log(2*pi)
            out[0] = (float)(cst + 0.5 * (double)sl + 0.5 * (double)sr);
        }
    }
}

extern "C" void kernel_launch(void* const* d_in, const int* in_sizes, int n_in,
                              void* d_out, int out_size, void* d_ws, size_t ws_size,
                              hipStream_t stream) {
    const float* r   = (const float*)d_in[0];
    const float* vol = (const float*)d_in[1];
    const float* a0  = (const float*)d_in[2];
    const float* a1  = (const float*)d_in[3];
    const float* rb0 = (const float*)d_in[4];
    const float* rb  = (const float*)d_in[5];
    const float* rw0 = (const float*)d_in[6];
    const float* rw  = (const float*)d_in[7];
    const float* rg  = (const float*)d_in[8];
    const float* rr  = (const float*)d_in[9];
    float* wsf = (float*)d_ws;
    float* out = (float*)d_out;
    const int T = in_sizes[0];
    const int n = T - 1;

    hipMemsetAsync(wsf, 0, 512, stream);   // zero accumulators + counters
    hipLaunchKernelGGL(k12_stats, dim3(256), dim3(256), 0, stream,
                       r, a0, a1, rb0, rb, rw0, rw, rg, rr, wsf, n, 256);
    const int nb = (n + NSTEP - 1) / NSTEP;
    hipLaunchKernelGGL(k_fused, dim3(nb), dim3(256), 0, stream,
                       r, vol, a0, a1, wsf, out, n, nb);
}

// Round 6
// 159.839 us; speedup vs baseline: 1.1722x; 1.1722x over previous
//
#include <hip/hip_runtime.h>
#include <math.h>

#define KCH 32          // channels k
#define Q 64            // taps q

// ---- MFMA conv params (round-4 verified core) ----
#define TB 256          // timesteps per conv block
#define TILE (TB + Q)   // staged entries (320)
#define USTR 352        // LDS staging stride (ushorts)

// ---- scan params ----
#define LCH 28          // chunk length (new steps)
#define WSC 12          // warm-up steps (contraction ~0.03/step -> 1e-18)
#define QPB 64          // chunks per 256-thread scan block (quad per chunk)

typedef __attribute__((ext_vector_type(8))) short short8;
typedef __attribute__((ext_vector_type(4))) float float4v;

__device__ __forceinline__ float sp_softplus(float x) {
    return (x > 15.f) ? x : log1pf(expf(x));
}

__device__ __forceinline__ unsigned int f2bf(float f) {
    union { float f; unsigned int u; } v; v.f = f;
    unsigned int u = v.u;
    return (u + 0x7FFFu + ((u >> 16) & 1u)) >> 16;   // RNE
}

__device__ __forceinline__ float bflo(unsigned int w) {
    return __int_as_float((int)(w << 16));
}
__device__ __forceinline__ float bfhi(unsigned int w) {
    return __int_as_float((int)(w & 0xFFFF0000u));
}

// butterfly sum over lanes within each quad (lanes 0..3), via DPP quad_perm
__device__ __forceinline__ float quad_sum4(float v) {
    int vi = __float_as_int(v);
    int p1 = __builtin_amdgcn_update_dpp(0, vi, 0xB1, 0xF, 0xF, true); // xor 1
    v += __int_as_float(p1);
    vi = __float_as_int(v);
    int p2 = __builtin_amdgcn_update_dpp(0, vi, 0x4E, 0xF, 0xF, true); // xor 2
    v += __int_as_float(p2);
    return v;
}

// ws layout (floats):
// [0]=sum_u2 [1]=sum_u2sq [2]=var [3]=sigma2_init [4]=acc_sumlog
// [5]=acc_sumratio [6]=beta0 [7]=counter_k1(int) [8..40)=beta [40..72)=rho
// [72..104)=w0 [104]=counter_scan(int)
// [4352..6400) : bf16 Wc[128][32] as ushort (4096 ush)
// [6656..)     : u2[n] fp32 ; then s[n][32] bf16 (n*16 float slots)
#define WOFF_BF16W 4352
#define WOFF_U2    6656

// --- K12: stats + (last block) param preprocessing -----------------------
extern "C" __global__ void k12_stats(const float* __restrict__ r,
                                     const float* __restrict__ a0p,
                                     const float* __restrict__ a1p,
                                     const float* __restrict__ rb0,
                                     const float* __restrict__ rb,
                                     const float* __restrict__ rw0,
                                     const float* __restrict__ rw,
                                     const float* __restrict__ rg,
                                     const float* __restrict__ rr,
                                     float* __restrict__ wsf,
                                     int n, int nblocks) {
    const float a0 = a0p[0], a1 = a1p[0];
    float s1 = 0.f, s2 = 0.f;
    for (int t = blockIdx.x * blockDim.x + threadIdx.x; t < n;
         t += gridDim.x * blockDim.x) {
        float u = r[t + 1] - a0 - a1 * r[t];
        float u2 = u * u;
        s1 += u2;
        s2 += u2 * u2;
    }
#pragma unroll
    for (int off = 32; off > 0; off >>= 1) {
        s1 += __shfl_down(s1, off);
        s2 += __shfl_down(s2, off);
    }
    __shared__ float b1[4], b2[4];
    __shared__ int lastflag;
    int wid = threadIdx.x >> 6;
    if ((threadIdx.x & 63) == 0) { b1[wid] = s1; b2[wid] = s2; }
    __syncthreads();
    if (threadIdx.x == 0) {
        float t1 = b1[0] + b1[1] + b1[2] + b1[3];
        float t2 = b2[0] + b2[1] + b2[2] + b2[3];
        atomicAdd(&wsf[0], t1);
        atomicAdd(&wsf[1], t2);
        __threadfence();
        int old = atomicAdd((int*)(wsf + 7), 1);
        lastflag = (old == nblocks - 1) ? 1 : 0;
    }
    __syncthreads();
    if (!lastflag) return;

    const int tid = threadIdx.x;
    if (tid == 0) {
        float t1 = atomicAdd(&wsf[0], 0.f);
        float t2 = atomicAdd(&wsf[1], 0.f);
        float nf = (float)n;
        float mean = t1 / nf;
        float var = fmaxf((t2 - nf * mean * mean) / (nf - 1.f), 0.f);
        wsf[2] = var;
        wsf[3] = var + 1e-6f;
        wsf[6] = sp_softplus(rb0[0]);
    }
    if (tid < KCH) {
        wsf[8 + tid]  = sp_softplus(rb[tid]);
        wsf[40 + tid] = sp_softplus(rr[tid]);
        wsf[72 + tid] = sp_softplus(rw0[tid]);
    }
    unsigned short* Wb = (unsigned short*)(wsf + WOFF_BF16W);
    for (int idx = tid; idx < 2 * KCH * Q; idx += blockDim.x) {
        int k = idx >> 5;        // 0..127 (taps already reversed)
        int i = idx & 31;        // channel
        float raw = (k < Q) ? rw[i * Q + (Q - 1 - k)]
                            : rg[i * Q + (Q - 1 - (k - Q))];
        Wb[idx] = (unsigned short)f2bf(sp_softplus(raw));
    }
}

// --- K3c: MFMA conv -> s[n][32] bf16 (packed dwords), u2[n] fp32 ---------
extern "C" __global__ void __launch_bounds__(256)
k3c_mfma(const float* __restrict__ r, const float* __restrict__ vol,
         const float* __restrict__ a0p, const float* __restrict__ a1p,
         const float* __restrict__ wsf,
         unsigned int* __restrict__ s32, float* __restrict__ u2_out, int n) {
    __shared__ unsigned short UV[4 * USTR];
    unsigned short* Ue = UV;
    unsigned short* Uo = UV + USTR;
    unsigned short* Ve = UV + 2 * USTR;
    unsigned short* Vo = UV + 3 * USTR;

    const int t0 = blockIdx.x * TB;
    const float a0 = a0p[0], a1 = a1p[0];
    const float var = wsf[2];

    for (int x = threadIdx.x; x < TILE; x += 256) {
        int f = t0 + x;                 // index into "full" (q + n) space
        float uval, vval;
        if (f < Q) {
            uval = var;
            vval = vol[0];
        } else {
            int t = f - Q;
            uval = 0.f; vval = 0.f;
            if (t < n) {
                float u = r[t + 1] - a0 - a1 * r[t];
                uval = u * u;
                vval = vol[t];
                u2_out[t] = uval;
            }
        }
        unsigned short ub = (unsigned short)f2bf(uval);
        unsigned short vb = (unsigned short)f2bf(vval);
        Ue[x] = ub; Ve[x] = vb;
        if (x > 0) { Uo[x - 1] = ub; Vo[x - 1] = vb; }
    }
    __syncthreads();

    const int tid = threadIdx.x;
    const int lane = tid & 63;
    const int ln = lane & 15;            // MFMA A-row / B,C,D col
    const int q4 = (lane >> 4) & 3;
    const int q8 = q4 * 8;
    const int wv = tid >> 6;

    // B-fragments: lane ln computes channels 2ln (acc0) and 2ln+1 (acc1)
    const unsigned short* Wb = (const unsigned short*)(wsf + WOFF_BF16W);
    short8 bf[4][2];
#pragma unroll
    for (int c = 0; c < 4; c++)
#pragma unroll
        for (int h = 0; h < 2; h++)
#pragma unroll
            for (int j = 0; j < 8; j++)
                bf[c][h][j] = (short)Wb[(c * 32 + q8 + j) * 32 + 2 * ln + h];
    const float w00 = wsf[72 + 2 * ln];
    const float w01 = wsf[72 + 2 * ln + 1];

    const unsigned int* pUe = (const unsigned int*)Ue;
    const unsigned int* pUo = (const unsigned int*)Uo;
    const unsigned int* pVe = (const unsigned int*)Ve;
    const unsigned int* pVo = (const unsigned int*)Vo;

#pragma unroll
    for (int wt = 0; wt < 4; wt++) {
        const int st = wv * 64 + wt * 16;
        float4v acc0 = {0.f, 0.f, 0.f, 0.f};
        float4v acc1 = {0.f, 0.f, 0.f, 0.f};
#pragma unroll
        for (int c = 0; c < 4; c++) {
            int e0 = st + ln + (c & 1) * 32 + q8;   // first of 8 A elements
            const unsigned int* pe = (c < 2) ? pUe : pVe;
            const unsigned int* po = (c < 2) ? pUo : pVo;
            const unsigned int* p = (e0 & 1) ? po : pe;
            int hx = e0 >> 1;
            union { unsigned int w[4]; short8 s; } A;
            A.w[0] = p[hx];
            A.w[1] = p[hx + 1];
            A.w[2] = p[hx + 2];
            A.w[3] = p[hx + 3];
            acc0 = __builtin_amdgcn_mfma_f32_16x16x32_bf16(A.s, bf[c][0], acc0, 0, 0, 0);
            acc1 = __builtin_amdgcn_mfma_f32_16x16x32_bf16(A.s, bf[c][1], acc1, 0, 0, 0);
        }
        const int rowb = t0 + st + q4 * 4;           // C/D: row=(lane>>4)*4+reg
#pragma unroll
        for (int rg_ = 0; rg_ < 4; rg_++) {
            int t = rowb + rg_;
            if (t < n) {
                unsigned int lo = f2bf(acc0[rg_] + w00);
                unsigned int hi = f2bf(acc1[rg_] + w01);
                s32[(size_t)t * 16 + ln] = lo | (hi << 16);
            }
        }
    }
}

// --- K3s: chunked scan over bf16 s, depth-4 prefetch, + final NLL --------
extern "C" __global__ void __launch_bounds__(256, 4)
k3s_scan(const unsigned short* __restrict__ s, const float* __restrict__ u2a,
         float* __restrict__ wsf, float* __restrict__ out,
         int n, int C, int nwaves) {
    const int tid = threadIdx.x;
    const int quad = tid >> 2;               // 0..63 within block
    const int laneq = tid & 3;
    const int chunk = blockIdx.x * QPB + quad;

    float rho_c[8], beta_c[8];
#pragma unroll
    for (int e = 0; e < 8; e++) {
        rho_c[e]  = wsf[40 + laneq * 8 + e];
        beta_c[e] = wsf[8 + laneq * 8 + e];
    }
    const float bconst = wsf[6] + 1e-8f;     // beta0 + 1e-8
    float sig = wsf[3];                      // sigma2_init warm start
    float sumlog = 0.f, sumratio = 0.f;

    int base = 0, warm = 0, send = 0;
    if (chunk < C) {
        const int cstart = chunk * LCH;
        warm = (chunk == 0) ? 0 : WSC;
        base = cstart - warm;
        send = warm + min(LCH, n - cstart);
    }
    const int send4 = (send + 3) & ~3;
    // row t lives at byte offset t*64; this lane reads 16 B at +laneq*16
    const char* sb = (const char*)s + laneq * 16;

    uint4 bq[4];
    float bu[4];
#pragma unroll
    for (int d = 0; d < 4; d++) {
        int tt = (d < send) ? (base + d) : 0;
        bq[d] = *reinterpret_cast<const uint4*>(sb + (size_t)tt * 64);
        bu[d] = u2a[tt];
    }

#define SCAN_STEP(d)                                                          \
    {                                                                         \
        const int s2 = s0 + (d);                                              \
        uint4 Wd = bq[d]; float uu = bu[d];                                   \
        int tn = base + s2 + 4; tn = (tn < n) ? tn : (n - 1);                 \
        bq[d] = *reinterpret_cast<const uint4*>(sb + (size_t)tn * 64);        \
        bu[d] = u2a[tn];                                                      \
        float h0 = fmaxf(fmaf(rho_c[0], sig, bflo(Wd.x)), 0.f);               \
        float h1 = fmaxf(fmaf(rho_c[1], sig, bfhi(Wd.x)), 0.f);               \
        float h2 = fmaxf(fmaf(rho_c[2], sig, bflo(Wd.y)), 0.f);               \
        float h3 = fmaxf(fmaf(rho_c[3], sig, bfhi(Wd.y)), 0.f);               \
        float h4 = fmaxf(fmaf(rho_c[4], sig, bflo(Wd.z)), 0.f);               \
        float h5 = fmaxf(fmaf(rho_c[5], sig, bfhi(Wd.z)), 0.f);               \
        float h6 = fmaxf(fmaf(rho_c[6], sig, bflo(Wd.w)), 0.f);               \
        float h7 = fmaxf(fmaf(rho_c[7], sig, bfhi(Wd.w)), 0.f);               \
        float p0 = beta_c[0] * h0;                                            \
        float p1 = beta_c[1] * h1;                                            \
        p0 = fmaf(beta_c[2], h2, p0);                                         \
        p1 = fmaf(beta_c[3], h3, p1);                                         \
        p0 = fmaf(beta_c[4], h4, p0);                                         \
        p1 = fmaf(beta_c[5], h5, p1);                                         \
        p0 = fmaf(beta_c[6], h6, p0);                                         \
        p1 = fmaf(beta_c[7], h7, p1);                                         \
        float dsum = quad_sum4(p0 + p1);                                      \
        sig = bconst + dsum;                                                  \
        float logv = __logf(sig);                                             \
        float rat = uu * __builtin_amdgcn_rcpf(sig);                          \
        bool live = (s2 >= warm) && (s2 < send);                              \
        sumlog += live ? logv : 0.f;                                          \
        sumratio += live ? rat : 0.f;                                         \
    }

    for (int s0 = 0; s0 < send4; s0 += 4) {
        SCAN_STEP(0)
        SCAN_STEP(1)
        SCAN_STEP(2)
        SCAN_STEP(3)
    }
#undef SCAN_STEP

    if (laneq != 0) { sumlog = 0.f; sumratio = 0.f; }
#pragma unroll
    for (int off = 32; off > 0; off >>= 1) {
        sumlog   += __shfl_down(sumlog, off);
        sumratio += __shfl_down(sumratio, off);
    }
    if ((tid & 63) == 0) {                   // one atomic pair per wave
        atomicAdd(&wsf[4], sumlog);
        atomicAdd(&wsf[5], sumratio);
        __threadfence();
        int old = atomicAdd((int*)(wsf + 104), 1);
        if (old == nwaves - 1) {
            float sl = atomicAdd(&wsf[4], 0.f);
            float sr = atomicAdd(&wsf[5], 0.f);
            double cst = 0.5 * (double)n * 1.8378770664093454;  // log(2*pi)
            out[0] = (float)(cst + 0.5 * (double)sl + 0.5 * (double)sr);
        }
    }
}

extern "C" void kernel_launch(void* const* d_in, const int* in_sizes, int n_in,
                              void* d_out, int out_size, void* d_ws, size_t ws_size,
                              hipStream_t stream) {
    const float* r   = (const float*)d_in[0];
    const float* vol = (const float*)d_in[1];
    const float* a0  = (const float*)d_in[2];
    const float* a1  = (const float*)d_in[3];
    const float* rb0 = (const float*)d_in[4];
    const float* rb  = (const float*)d_in[5];
    const float* rw0 = (const float*)d_in[6];
    const float* rw  = (const float*)d_in[7];
    const float* rg  = (const float*)d_in[8];
    const float* rr  = (const float*)d_in[9];
    float* wsf = (float*)d_ws;
    float* out = (float*)d_out;
    const int T = in_sizes[0];
    const int n = T - 1;

    // ws: params [0,6656); u2[n] fp32 at 6656; s[n][32] bf16 after (16 fl/row)
    const size_t u2_off = WOFF_U2;
    const size_t s_off  = u2_off + (size_t)((n + 255) & ~255);
    float* u2a = wsf + u2_off;
    unsigned int* s32 = (unsigned int*)(wsf + s_off);

    hipMemsetAsync(wsf, 0, 512, stream);   // zero accumulators + counters
    hipLaunchKernelGGL(k12_stats, dim3(256), dim3(256), 0, stream,
                       r, a0, a1, rb0, rb, rw0, rw, rg, rr, wsf, n, 256);
    const int nb_conv = (n + TB - 1) / TB;
    hipLaunchKernelGGL(k3c_mfma, dim3(nb_conv), dim3(256), 0, stream,
                       r, vol, a0, a1, wsf, s32, u2a, n);
    const int C = (n + LCH - 1) / LCH;
    const int nb_scan = (C + QPB - 1) / QPB;
    hipLaunchKernelGGL(k3s_scan, dim3(nb_scan), dim3(256), 0, stream,
                       (const unsigned short*)s32, u2a, wsf, out,
                       n, C, nb_scan * 4);
}